// Round 5
// baseline (307.159 us; speedup 1.0000x reference)
//
#include <hip/hip_runtime.h>

#define BLOCK 128
#define GRID 4096   // GRID * PTILE == NPIX exactly

namespace {
constexpr int C = 21;
constexpr int HW = 512 * 512;          // 262144 = 2^18
constexpr int NPIX = 8 * HW;           // 2097152
constexpr int PTILE = 512;             // pixels per block tile (= BLOCK*4)
constexpr float EPS = 1e-8f;
constexpr int WS_CNT = C * C;
constexpr int WS_LOGP = C * C + C;
constexpr int ACC_USED = C * C + C + 1;   // 463
constexpr int ACC_STRIDE = 464;
constexpr int MAX_COPIES = 64;
}

// Async global->LDS DMA, 16B per lane, zero VGPR destinations. LDS dest must
// be wave-uniform (HW adds lane*16); global src is per-lane.
__device__ __forceinline__ void lds_dma16(const float* g, float* l) {
    __builtin_amdgcn_global_load_lds(
        (const __attribute__((address_space(1))) void*)g,
        (__attribute__((address_space(3))) void*)l,
        16, 0, 0);
}

__global__ __launch_bounds__(BLOCK) void wce_main(const float* __restrict__ inp,
                                                  const float* __restrict__ tgt,
                                                  float* __restrict__ acc,
                                                  int copy_mask) {
    __shared__ __align__(16) float buf[C][PTILE];   // 42 KB staging tile
    __shared__ float sS[C * C];
    __shared__ float sCnt[C];
    __shared__ float sRed[BLOCK / 64];

    const int tid = threadIdx.x;
    const int wid = tid >> 6;              // wave id (0/1), uniform per wave

    for (int i = tid; i < C * C; i += BLOCK) sS[i] = 0.f;
    if (tid < C) sCnt[tid] = 0.f;

    const int px0 = blockIdx.x * PTILE;
    const int n = px0 >> 18;               // / HW
    const int hw = px0 & (HW - 1);
    const float* __restrict__ tbase = tgt + (size_t)n * (size_t)(C * HW) + hw;
    const float* __restrict__ ibase = inp + (size_t)n * (size_t)(C * HW) + hw;
    const int lane4 = tid * 4;             // this thread's float offset in tile

    // ---- phase 1: DMA all 21 target channel spans (21 KB/wave in flight) ----
#pragma unroll
    for (int c = 0; c < C; ++c)
        lds_dma16(tbase + (size_t)c * HW + lane4, &buf[c][wid * 256]);
    asm volatile("s_waitcnt vmcnt(0)" ::: "memory");
    __syncthreads();

    // ---- phase 2: per-pixel target argmax (thread owns 4 consecutive px) ----
    float4 bv = reinterpret_cast<const float4*>(&buf[0][0])[tid];
    int bx = 0, by = 0, bz = 0, bw = 0;
#pragma unroll
    for (int c = 1; c < C; ++c) {
        const float4 t = reinterpret_cast<const float4*>(&buf[c][0])[tid];
        if (t.x > bv.x) { bv.x = t.x; bx = c; }
        if (t.y > bv.y) { bv.y = t.y; by = c; }
        if (t.z > bv.z) { bv.z = t.z; bz = c; }
        if (t.w > bv.w) { bv.w = t.w; bw = c; }
    }
    __syncthreads();   // everyone done reading target tile before overwrite

    // ---- phase 3: DMA all 21 input channel spans into same buffer ----
#pragma unroll
    for (int c = 0; c < C; ++c)
        lds_dma16(ibase + (size_t)c * HW + lane4, &buf[c][wid * 256]);
    asm volatile("s_waitcnt vmcnt(0)" ::: "memory");
    __syncthreads();

    // ---- phase 4a: max + x[label] sweep ----
    float4 m = reinterpret_cast<const float4*>(&buf[0][0])[tid];
    float4 xlab = m;
#pragma unroll
    for (int c = 1; c < C; ++c) {
        const float4 v = reinterpret_cast<const float4*>(&buf[c][0])[tid];
        m.x = fmaxf(m.x, v.x);
        m.y = fmaxf(m.y, v.y);
        m.z = fmaxf(m.z, v.z);
        m.w = fmaxf(m.w, v.w);
        if (bx == c) xlab.x = v.x;
        if (by == c) xlab.y = v.y;
        if (bz == c) xlab.z = v.z;
        if (bw == c) xlab.w = v.w;
    }

    // ---- phase 4b: exp-sum sweep ----
    float4 s = make_float4(0.f, 0.f, 0.f, 0.f);
#pragma unroll
    for (int c = 0; c < C; ++c) {
        const float4 v = reinterpret_cast<const float4*>(&buf[c][0])[tid];
        s.x += __expf(v.x - m.x);
        s.y += __expf(v.y - m.y);
        s.z += __expf(v.z - m.z);
        s.w += __expf(v.w - m.w);
    }

    float lp = (xlab.x - m.x - __logf(s.x))
             + (xlab.y - m.y - __logf(s.y))
             + (xlab.z - m.z - __logf(s.z))
             + (xlab.w - m.w - __logf(s.w));

    // ---- phase 4c: p-scatter sweep (recompute exp, scale by 1/s) ----
    const float ix = 1.f / s.x, iy = 1.f / s.y, iz = 1.f / s.z, iw = 1.f / s.w;
#pragma unroll
    for (int c = 0; c < C; ++c) {
        const float4 v = reinterpret_cast<const float4*>(&buf[c][0])[tid];
        unsafeAtomicAdd(&sS[c * C + bx], __expf(v.x - m.x) * ix);
        unsafeAtomicAdd(&sS[c * C + by], __expf(v.y - m.y) * iy);
        unsafeAtomicAdd(&sS[c * C + bz], __expf(v.z - m.z) * iz);
        unsafeAtomicAdd(&sS[c * C + bw], __expf(v.w - m.w) * iw);
    }
    unsafeAtomicAdd(&sCnt[bx], 1.f);
    unsafeAtomicAdd(&sCnt[by], 1.f);
    unsafeAtomicAdd(&sCnt[bz], 1.f);
    unsafeAtomicAdd(&sCnt[bw], 1.f);

    // ---- block reduce logpy ----
#pragma unroll
    for (int off = 32; off > 0; off >>= 1) lp += __shfl_down(lp, off);
    if ((tid & 63) == 0) sRed[wid] = lp;
    __syncthreads();   // covers sRed AND all LDS atomics above

    // ---- flush block partials to one of `copies` global accumulators ----
    float* __restrict__ a = acc + (size_t)(blockIdx.x & copy_mask) * ACC_STRIDE;
    for (int i = tid; i < C * C; i += BLOCK) unsafeAtomicAdd(&a[i], sS[i]);
    if (tid < C) unsafeAtomicAdd(&a[WS_CNT + tid], sCnt[tid]);
    if (tid == 0) {
        float tt = 0.f;
#pragma unroll
        for (int wv = 0; wv < BLOCK / 64; ++wv) tt += sRed[wv];
        unsafeAtomicAdd(&a[WS_LOGP], tt);
    }
}

__global__ void wce_final(const float* __restrict__ acc, float* __restrict__ out,
                          int copies) {
    __shared__ float tot[ACC_USED];
    __shared__ float red[8];
    const int tid = threadIdx.x;

    for (int i = tid; i < ACC_USED; i += 512) {
        float s = 0.f;
        for (int k = 0; k < copies; ++k) s += acc[(size_t)k * ACC_STRIDE + i];
        tot[i] = s;
    }
    __syncthreads();

    float partial = 0.f;
    if (tid < C * C) {
        const int i = tid / C;
        const int j = tid - i * C;
        if (i != j) {
            const float ci = tot[WS_CNT + i], cj = tot[WS_CNT + j];
            if (ci > 0.f && cj > 0.f) {
                const float mcc = tot[i * C + i] / ci - tot[i * C + j] / cj;
                partial = -0.5f * __logf(0.5f * mcc + 0.5f + EPS);
            }
        }
    }
#pragma unroll
    for (int off = 32; off > 0; off >>= 1) partial += __shfl_down(partial, off);
    if ((tid & 63) == 0) red[tid >> 6] = partial;
    __syncthreads();

    if (tid == 0) {
        float lossd = 0.f;
#pragma unroll
        for (int wv = 0; wv < 8; ++wv) lossd += red[wv];
        const float loss = -tot[WS_LOGP] / (float)NPIX;
        out[0] = loss + lossd;
    }
}

extern "C" void kernel_launch(void* const* d_in, const int* in_sizes, int n_in,
                              void* d_out, int out_size, void* d_ws, size_t ws_size,
                              hipStream_t stream) {
    const float* inp = (const float*)d_in[0];
    const float* tgt = (const float*)d_in[1];
    float* acc = (float*)d_ws;
    float* out = (float*)d_out;

    int copies = 1;
    const size_t per = (size_t)ACC_STRIDE * sizeof(float);
    while (copies * 2 <= MAX_COPIES && (size_t)(copies * 2) * per <= ws_size) copies *= 2;

    hipMemsetAsync(acc, 0, (size_t)copies * per, stream);
    wce_main<<<GRID, BLOCK, 0, stream>>>(inp, tgt, acc, copies - 1);
    wce_final<<<1, 512, 0, stream>>>(acc, out, copies);
}